// Round 1
// baseline (11320.481 us; speedup 1.0000x reference)
//
#include <hip/hip_runtime.h>
#include <math.h>

#define NODES 81
#define B_SZ 512
#define T_STEPS 12
#define NSEQ (B_SZ * NODES)   // 41472
#define HID 128
#define GATES 512
#define G 16                  // sequences per block

// ---------------------------------------------------------------------------
// Prep: transpose weight matrices to k-major [128][512] for coalesced float4
// streaming in the main kernel; fold bias pairs.
// ---------------------------------------------------------------------------
__global__ void prep_kernel(const float* __restrict__ Whh0,
                            const float* __restrict__ Wih1,
                            const float* __restrict__ Whh1,
                            const float* __restrict__ bih0, const float* __restrict__ bhh0,
                            const float* __restrict__ bih1, const float* __restrict__ bhh1,
                            float* __restrict__ WhhT0,
                            float* __restrict__ WihT1,
                            float* __restrict__ WhhT1,
                            float* __restrict__ b0,
                            float* __restrict__ b1)
{
    int idx = blockIdx.x * 256 + threadIdx.x;
    if (idx < 65536) {
        int k = idx >> 9, j = idx & 511;
        WhhT0[idx] = Whh0[j * HID + k];
    } else if (idx < 131072) {
        int r = idx - 65536; int k = r >> 9, j = r & 511;
        WihT1[r] = Wih1[j * HID + k];
    } else if (idx < 196608) {
        int r = idx - 131072; int k = r >> 9, j = r & 511;
        WhhT1[r] = Whh1[j * HID + k];
    } else if (idx < 197120) {
        int j = idx - 196608;
        b0[j] = bih0[j] + bhh0[j];
    } else if (idx < 197632) {
        int j = idx - 197120;
        b1[j] = bih1[j] + bhh1[j];
    }
}

// ---------------------------------------------------------------------------
// income = einsum('bta,an->bnt'); stored t-major: x[t][seq], seq = b*81+n
// ---------------------------------------------------------------------------
__global__ void income_kernel(const float* __restrict__ g_data,
                              const float* __restrict__ w,
                              float* __restrict__ x)
{
    int idx = blockIdx.x * 256 + threadIdx.x;   // 512*12*81 = 497664 exactly
    int n = idx % NODES;
    int r = idx / NODES;
    int t = r % T_STEPS;
    int b = r / T_STEPS;
    const float* grow = g_data + (b * T_STEPS + t) * NODES;
    float s = 0.f;
    #pragma unroll 3
    for (int a = 0; a < NODES; ++a)
        s += grow[a] * w[a * NODES + n];
    x[t * NSEQ + b * NODES + n] = s;
}

// ---------------------------------------------------------------------------
// Fused 2-layer LSTM over T=12 + FC head. One block = 16 sequences.
// Thread roles (tid 0..255): g = tid&15 (sequence), jg = tid>>4 (gate group of
// 32 gates). Matmul phase: each thread accumulates its 32 gates for its
// sequence. Update phase: thread owns h/c elements [jg*8, jg*8+8) of seq g.
// ---------------------------------------------------------------------------
__global__ __launch_bounds__(256) void lstm_main(
    const float* __restrict__ x,       // [12][NSEQ]
    const float* __restrict__ Wih0,    // [512]
    const float* __restrict__ WhhT0,   // [128][512]
    const float* __restrict__ WihT1,   // [128][512]
    const float* __restrict__ WhhT1,   // [128][512]
    const float* __restrict__ b0,      // [512]
    const float* __restrict__ b1,      // [512]
    const float* __restrict__ fc1_w,   // [32][128]
    const float* __restrict__ fc1_b,   // [32]
    const float* __restrict__ fc2_w,   // [32]
    const float* __restrict__ fc2_b,   // [1]
    float* __restrict__ out)           // [NSEQ]
{
    __shared__ float h0[G][HID + 1];
    __shared__ float h1[G][HID + 1];
    __shared__ float ga[G][GATES + 1];

    const int tid = threadIdx.x;
    const int g = tid & 15;
    const int jg = tid >> 4;           // 0..15
    const int jbase = jg * 32;
    const int ks = jg * 8;
    const int gtype = jg >> 2;         // 0=i 1=f 2=g(cell) 3=o
    const int seq0 = blockIdx.x * G;

    float c0r[8], c1r[8];
    #pragma unroll
    for (int q = 0; q < 8; ++q) { c0r[q] = 0.f; c1r[q] = 0.f; }
    #pragma unroll
    for (int q = 0; q < 8; ++q) { h0[g][ks + q] = 0.f; h1[g][ks + q] = 0.f; }
    __syncthreads();

    float acc[32];

    for (int t = 0; t < T_STEPS; ++t) {
        // ===== layer 0: gates = x*Wih0 + h0@Whh0^T + b0 =====
        {
            float xv = x[t * NSEQ + seq0 + g];
            #pragma unroll
            for (int jj = 0; jj < 32; ++jj)
                acc[jj] = xv * Wih0[jbase + jj] + b0[jbase + jj];
            for (int k = 0; k < HID; ++k) {
                float hk = h0[g][k];
                const float4* w4 = (const float4*)(WhhT0 + k * GATES + jbase);
                #pragma unroll
                for (int q = 0; q < 8; ++q) {
                    float4 w = w4[q];
                    acc[4*q+0] += hk * w.x;
                    acc[4*q+1] += hk * w.y;
                    acc[4*q+2] += hk * w.z;
                    acc[4*q+3] += hk * w.w;
                }
            }
            if (gtype == 2) {
                #pragma unroll
                for (int jj = 0; jj < 32; ++jj) ga[g][jbase + jj] = tanhf(acc[jj]);
            } else {
                #pragma unroll
                for (int jj = 0; jj < 32; ++jj) ga[g][jbase + jj] = 1.f / (1.f + expf(-acc[jj]));
            }
        }
        __syncthreads();
        // update c0, h0
        #pragma unroll
        for (int q = 0; q < 8; ++q) {
            int k = ks + q;
            float i_ = ga[g][k];
            float f_ = ga[g][HID + k];
            float g_ = ga[g][2 * HID + k];
            float o_ = ga[g][3 * HID + k];
            float c = f_ * c0r[q] + i_ * g_;
            c0r[q] = c;
            h0[g][k] = o_ * tanhf(c);
        }
        __syncthreads();

        // ===== layer 1: gates = h0@Wih1^T + h1@Whh1^T + b1 =====
        {
            #pragma unroll
            for (int jj = 0; jj < 32; ++jj) acc[jj] = b1[jbase + jj];
            for (int k = 0; k < HID; ++k) {
                float hk = h0[g][k];
                const float4* w4 = (const float4*)(WihT1 + k * GATES + jbase);
                #pragma unroll
                for (int q = 0; q < 8; ++q) {
                    float4 w = w4[q];
                    acc[4*q+0] += hk * w.x;
                    acc[4*q+1] += hk * w.y;
                    acc[4*q+2] += hk * w.z;
                    acc[4*q+3] += hk * w.w;
                }
            }
            for (int k = 0; k < HID; ++k) {
                float hk = h1[g][k];
                const float4* w4 = (const float4*)(WhhT1 + k * GATES + jbase);
                #pragma unroll
                for (int q = 0; q < 8; ++q) {
                    float4 w = w4[q];
                    acc[4*q+0] += hk * w.x;
                    acc[4*q+1] += hk * w.y;
                    acc[4*q+2] += hk * w.z;
                    acc[4*q+3] += hk * w.w;
                }
            }
            if (gtype == 2) {
                #pragma unroll
                for (int jj = 0; jj < 32; ++jj) ga[g][jbase + jj] = tanhf(acc[jj]);
            } else {
                #pragma unroll
                for (int jj = 0; jj < 32; ++jj) ga[g][jbase + jj] = 1.f / (1.f + expf(-acc[jj]));
            }
        }
        __syncthreads();
        // update c1, h1
        #pragma unroll
        for (int q = 0; q < 8; ++q) {
            int k = ks + q;
            float i_ = ga[g][k];
            float f_ = ga[g][HID + k];
            float g_ = ga[g][2 * HID + k];
            float o_ = ga[g][3 * HID + k];
            float c = f_ * c1r[q] + i_ * g_;
            c1r[q] = c;
            h1[g][k] = o_ * tanhf(c);
        }
        __syncthreads();
    }

    // ===== FC head: relu(relu(h1 @ fc1^T + b) @ fc2^T + b) =====
    for (int task = tid; task < G * 32; task += 256) {
        int gg = task & 15;
        int j = task >> 4;           // 0..31
        float s = fc1_b[j];
        const float* wrow = fc1_w + j * HID;
        #pragma unroll 4
        for (int k = 0; k < HID; ++k) s += h1[gg][k] * wrow[k];
        ga[gg][j] = fmaxf(s, 0.f);
    }
    __syncthreads();
    if (tid < G) {
        float s = fc2_b[0];
        #pragma unroll
        for (int j = 0; j < 32; ++j) s += ga[tid][j] * fc2_w[j];
        out[seq0 + tid] = fmaxf(s, 0.f);
    }
}

// ---------------------------------------------------------------------------
extern "C" void kernel_launch(void* const* d_in, const int* in_sizes, int n_in,
                              void* d_out, int out_size, void* d_ws, size_t ws_size,
                              hipStream_t stream)
{
    const float* g_data = (const float*)d_in[0];
    const float* weights = (const float*)d_in[1];
    const float* Wih0   = (const float*)d_in[2];
    const float* Whh0   = (const float*)d_in[3];
    const float* bih0   = (const float*)d_in[4];
    const float* bhh0   = (const float*)d_in[5];
    const float* Wih1   = (const float*)d_in[6];
    const float* Whh1   = (const float*)d_in[7];
    const float* bih1   = (const float*)d_in[8];
    const float* bhh1   = (const float*)d_in[9];
    const float* fc1_w  = (const float*)d_in[10];
    const float* fc1_b  = (const float*)d_in[11];
    const float* fc2_w  = (const float*)d_in[12];
    const float* fc2_b  = (const float*)d_in[13];
    float* out = (float*)d_out;

    float* ws     = (float*)d_ws;
    float* x      = ws;                  // 497664 floats
    float* WhhT0  = x + NSEQ * T_STEPS;  // 65536
    float* WihT1  = WhhT0 + 65536;       // 65536
    float* WhhT1  = WihT1 + 65536;       // 65536
    float* b0     = WhhT1 + 65536;       // 512
    float* b1     = b0 + 512;            // 512

    prep_kernel<<<772, 256, 0, stream>>>(Whh0, Wih1, Whh1, bih0, bhh0, bih1, bhh1,
                                         WhhT0, WihT1, WhhT1, b0, b1);
    income_kernel<<<1944, 256, 0, stream>>>(g_data, weights, x);
    lstm_main<<<NSEQ / G, 256, 0, stream>>>(x, Wih0, WhhT0, WihT1, WhhT1, b0, b1,
                                            fc1_w, fc1_b, fc2_w, fc2_b, out);
}

// Round 2
// 3831.297 us; speedup vs baseline: 2.9547x; 2.9547x over previous
//
#include <hip/hip_runtime.h>
#include <math.h>

#define NODES 81
#define B_SZ 512
#define T_STEPS 12
#define NSEQ (B_SZ * NODES)   // 41472
#define HID 128
#define GATES 512
#define G 32                  // sequences per block
#define HPAD 36               // padded row stride for hT (16B aligned, conflict-free)

// ---------------------------------------------------------------------------
// Prep: build gate-permuted, k-major weights.
// New gate index j' = k_hid*4 + type  (type: 0=i 1=f 2=g 3=o; orig j = type*128+k_hid)
// WT[k][j'] = W[j][k]  stored [128][512].
// ---------------------------------------------------------------------------
__global__ void prep_kernel(const float* __restrict__ Whh0,
                            const float* __restrict__ Wih1,
                            const float* __restrict__ Whh1,
                            const float* __restrict__ Wih0,
                            const float* __restrict__ bih0, const float* __restrict__ bhh0,
                            const float* __restrict__ bih1, const float* __restrict__ bhh1,
                            float* __restrict__ WT0,
                            float* __restrict__ WT1i,
                            float* __restrict__ WT1h,
                            float* __restrict__ wih0p,
                            float* __restrict__ b0p,
                            float* __restrict__ b1p)
{
    int idx = blockIdx.x * 256 + threadIdx.x;   // 198144 total, exact
    if (idx < 65536) {
        int k = idx >> 9, jp = idx & 511;
        int kh = jp >> 2, ty = jp & 3;
        WT0[idx] = Whh0[(ty * 128 + kh) * 128 + k];
    } else if (idx < 131072) {
        int r = idx - 65536;
        int k = r >> 9, jp = r & 511;
        int kh = jp >> 2, ty = jp & 3;
        WT1i[r] = Wih1[(ty * 128 + kh) * 128 + k];
    } else if (idx < 196608) {
        int r = idx - 131072;
        int k = r >> 9, jp = r & 511;
        int kh = jp >> 2, ty = jp & 3;
        WT1h[r] = Whh1[(ty * 128 + kh) * 128 + k];
    } else if (idx < 197120) {
        int jp = idx - 196608;
        int kh = jp >> 2, ty = jp & 3;
        wih0p[jp] = Wih0[ty * 128 + kh];
    } else if (idx < 197632) {
        int jp = idx - 197120;
        int kh = jp >> 2, ty = jp & 3;
        int j = ty * 128 + kh;
        b0p[jp] = bih0[j] + bhh0[j];
    } else if (idx < 198144) {
        int jp = idx - 197632;
        int kh = jp >> 2, ty = jp & 3;
        int j = ty * 128 + kh;
        b1p[jp] = bih1[j] + bhh1[j];
    }
}

// ---------------------------------------------------------------------------
// income = einsum('bta,an->bnt'); stored t-major: x[t][seq], seq = b*81+n
// ---------------------------------------------------------------------------
__global__ void income_kernel(const float* __restrict__ g_data,
                              const float* __restrict__ w,
                              float* __restrict__ x)
{
    int idx = blockIdx.x * 256 + threadIdx.x;   // 497664 exactly
    int n = idx % NODES;
    int r = idx / NODES;
    int t = r % T_STEPS;
    int b = r / T_STEPS;
    const float* grow = g_data + (b * T_STEPS + t) * NODES;
    float s = 0.f;
    #pragma unroll 3
    for (int a = 0; a < NODES; ++a)
        s += grow[a] * w[a * NODES + n];
    x[t * NSEQ + b * NODES + n] = s;
}

__device__ __forceinline__ float sigf(float v) { return 1.f / (1.f + expf(-v)); }

// 16 FMAs of one h-scalar against 4 weight float4s into acc row S
#define ROW16(S, HS, W0, W1, W2, W3) \
    a[(S)*16+ 0] += (HS)*(W0).x; a[(S)*16+ 1] += (HS)*(W0).y; a[(S)*16+ 2] += (HS)*(W0).z; a[(S)*16+ 3] += (HS)*(W0).w; \
    a[(S)*16+ 4] += (HS)*(W1).x; a[(S)*16+ 5] += (HS)*(W1).y; a[(S)*16+ 6] += (HS)*(W1).z; a[(S)*16+ 7] += (HS)*(W1).w; \
    a[(S)*16+ 8] += (HS)*(W2).x; a[(S)*16+ 9] += (HS)*(W2).y; a[(S)*16+10] += (HS)*(W2).z; a[(S)*16+11] += (HS)*(W2).w; \
    a[(S)*16+12] += (HS)*(W3).x; a[(S)*16+13] += (HS)*(W3).y; a[(S)*16+14] += (HS)*(W3).z; a[(S)*16+15] += (HS)*(W3).w;

#define INIT16(S, HS, W0, W1, W2, W3) \
    a[(S)*16+ 0] = (HS)*(W0).x; a[(S)*16+ 1] = (HS)*(W0).y; a[(S)*16+ 2] = (HS)*(W0).z; a[(S)*16+ 3] = (HS)*(W0).w; \
    a[(S)*16+ 4] = (HS)*(W1).x; a[(S)*16+ 5] = (HS)*(W1).y; a[(S)*16+ 6] = (HS)*(W1).z; a[(S)*16+ 7] = (HS)*(W1).w; \
    a[(S)*16+ 8] = (HS)*(W2).x; a[(S)*16+ 9] = (HS)*(W2).y; a[(S)*16+10] = (HS)*(W2).z; a[(S)*16+11] = (HS)*(W2).w; \
    a[(S)*16+12] = (HS)*(W3).x; a[(S)*16+13] = (HS)*(W3).y; a[(S)*16+14] = (HS)*(W3).z; a[(S)*16+15] = (HS)*(W3).w;

// ---------------------------------------------------------------------------
// Fused 2-layer LSTM + FC head. Block = 256 threads = 32 jg-groups x 8 sg-groups.
// Thread (jg, sg) owns 4 seqs (sg*4..+4) x 4 hidden units (jg*4..+4) x 4 gates.
// h state transposed in LDS: hT[k][seq], stride HPAD.
// ---------------------------------------------------------------------------
__global__ __launch_bounds__(256, 3) void lstm_main(
    const float* __restrict__ x,       // [12][NSEQ]
    const float* __restrict__ WT0,     // [128][512]
    const float* __restrict__ WT1i,    // [128][512]
    const float* __restrict__ WT1h,    // [128][512]
    const float* __restrict__ wih0p,   // [512]
    const float* __restrict__ b0p,     // [512]
    const float* __restrict__ b1p,     // [512]
    const float* __restrict__ fc1_w,   // [32][128]
    const float* __restrict__ fc1_b,   // [32]
    const float* __restrict__ fc2_w,   // [32]
    const float* __restrict__ fc2_b,   // [1]
    float* __restrict__ out)           // [NSEQ]
{
    __shared__ float hT0[HID * HPAD];
    __shared__ float hT1[HID * HPAD];

    const int tid = threadIdx.x;
    const int sg = tid & 7;
    const int jg = tid >> 3;           // 0..31
    const int sg4 = sg * 4;
    const int jbase = jg * 16;
    const int seq0 = blockIdx.x * G;

    for (int i = tid; i < HID * HPAD; i += 256) { hT0[i] = 0.f; hT1[i] = 0.f; }

    float c0[16], c1[16];              // [s*4+u]
    #pragma unroll
    for (int i = 0; i < 16; ++i) { c0[i] = 0.f; c1[i] = 0.f; }
    __syncthreads();

    float a[64];                       // acc [s*16 + u*4 + type]
    float hnew[16];                    // [s*4+u]
    float bb[16];

    for (int t = 0; t < T_STEPS; ++t) {
        // ===== layer 0 matmul: a = x*wih0' + h0 @ WT0 =====
        {
            float4 xv = *(const float4*)&x[t * NSEQ + seq0 + sg4];
            const float* wi = wih0p + jbase;
            float4 w0 = *(const float4*)(wi + 0);
            float4 w1 = *(const float4*)(wi + 4);
            float4 w2 = *(const float4*)(wi + 8);
            float4 w3 = *(const float4*)(wi + 12);
            INIT16(0, xv.x, w0, w1, w2, w3)
            INIT16(1, xv.y, w0, w1, w2, w3)
            INIT16(2, xv.z, w0, w1, w2, w3)
            INIT16(3, xv.w, w0, w1, w2, w3)
        }
        #pragma unroll 2
        for (int k = 0; k < HID; ++k) {
            float4 h4 = *(const float4*)&hT0[k * HPAD + sg4];
            const float* wr = WT0 + k * GATES + jbase;
            float4 w0 = *(const float4*)(wr + 0);
            float4 w1 = *(const float4*)(wr + 4);
            float4 w2 = *(const float4*)(wr + 8);
            float4 w3 = *(const float4*)(wr + 12);
            ROW16(0, h4.x, w0, w1, w2, w3)
            ROW16(1, h4.y, w0, w1, w2, w3)
            ROW16(2, h4.z, w0, w1, w2, w3)
            ROW16(3, h4.w, w0, w1, w2, w3)
        }
        // ===== layer 0 update (registers) =====
        *(float4*)&bb[0]  = *(const float4*)(b0p + jbase + 0);
        *(float4*)&bb[4]  = *(const float4*)(b0p + jbase + 4);
        *(float4*)&bb[8]  = *(const float4*)(b0p + jbase + 8);
        *(float4*)&bb[12] = *(const float4*)(b0p + jbase + 12);
        #pragma unroll
        for (int s = 0; s < 4; ++s)
            #pragma unroll
            for (int u = 0; u < 4; ++u) {
                float iv = sigf(a[s*16+u*4+0] + bb[u*4+0]);
                float fv = sigf(a[s*16+u*4+1] + bb[u*4+1]);
                float gv = tanhf(a[s*16+u*4+2] + bb[u*4+2]);
                float ov = sigf(a[s*16+u*4+3] + bb[u*4+3]);
                float c = fv * c0[s*4+u] + iv * gv;
                c0[s*4+u] = c;
                hnew[s*4+u] = ov * tanhf(c);
            }
        __syncthreads();               // all reads of hT0 done
        #pragma unroll
        for (int u = 0; u < 4; ++u)
            *(float4*)&hT0[(jg*4+u) * HPAD + sg4] =
                make_float4(hnew[0*4+u], hnew[1*4+u], hnew[2*4+u], hnew[3*4+u]);
        __syncthreads();               // new h0 visible

        // ===== layer 1 matmul: a = h0 @ WT1i + h1 @ WT1h =====
        #pragma unroll
        for (int i = 0; i < 64; ++i) a[i] = 0.f;
        #pragma unroll 2
        for (int k = 0; k < HID; ++k) {
            float4 h04 = *(const float4*)&hT0[k * HPAD + sg4];
            float4 h14 = *(const float4*)&hT1[k * HPAD + sg4];
            const float* wri = WT1i + k * GATES + jbase;
            const float* wrh = WT1h + k * GATES + jbase;
            float4 wi0 = *(const float4*)(wri + 0);
            float4 wi1 = *(const float4*)(wri + 4);
            float4 wi2 = *(const float4*)(wri + 8);
            float4 wi3 = *(const float4*)(wri + 12);
            ROW16(0, h04.x, wi0, wi1, wi2, wi3)
            ROW16(1, h04.y, wi0, wi1, wi2, wi3)
            ROW16(2, h04.z, wi0, wi1, wi2, wi3)
            ROW16(3, h04.w, wi0, wi1, wi2, wi3)
            float4 wh0 = *(const float4*)(wrh + 0);
            float4 wh1 = *(const float4*)(wrh + 4);
            float4 wh2 = *(const float4*)(wrh + 8);
            float4 wh3 = *(const float4*)(wrh + 12);
            ROW16(0, h14.x, wh0, wh1, wh2, wh3)
            ROW16(1, h14.y, wh0, wh1, wh2, wh3)
            ROW16(2, h14.z, wh0, wh1, wh2, wh3)
            ROW16(3, h14.w, wh0, wh1, wh2, wh3)
        }
        // ===== layer 1 update =====
        *(float4*)&bb[0]  = *(const float4*)(b1p + jbase + 0);
        *(float4*)&bb[4]  = *(const float4*)(b1p + jbase + 4);
        *(float4*)&bb[8]  = *(const float4*)(b1p + jbase + 8);
        *(float4*)&bb[12] = *(const float4*)(b1p + jbase + 12);
        #pragma unroll
        for (int s = 0; s < 4; ++s)
            #pragma unroll
            for (int u = 0; u < 4; ++u) {
                float iv = sigf(a[s*16+u*4+0] + bb[u*4+0]);
                float fv = sigf(a[s*16+u*4+1] + bb[u*4+1]);
                float gv = tanhf(a[s*16+u*4+2] + bb[u*4+2]);
                float ov = sigf(a[s*16+u*4+3] + bb[u*4+3]);
                float c = fv * c1[s*4+u] + iv * gv;
                c1[s*4+u] = c;
                hnew[s*4+u] = ov * tanhf(c);
            }
        __syncthreads();               // all reads of hT1 done
        #pragma unroll
        for (int u = 0; u < 4; ++u)
            *(float4*)&hT1[(jg*4+u) * HPAD + sg4] =
                make_float4(hnew[0*4+u], hnew[1*4+u], hnew[2*4+u], hnew[3*4+u]);
    }
    __syncthreads();                   // final h1 visible

    // ===== FC head =====
    float hidv[4];
    #pragma unroll
    for (int r = 0; r < 4; ++r) {
        int task = tid + r * 256;      // 0..1023 = 32 seq x 32 j
        int sL = task & 31, j = task >> 5;
        float ssum = fc1_b[j];
        const float* wrow = fc1_w + j * HID;
        #pragma unroll 8
        for (int k = 0; k < HID; ++k) ssum += hT1[k * HPAD + sL] * wrow[k];
        hidv[r] = fmaxf(ssum, 0.f);
    }
    __syncthreads();
    #pragma unroll
    for (int r = 0; r < 4; ++r) {
        int task = tid + r * 256;
        hT0[(task & 31) * HPAD + (task >> 5)] = hidv[r];   // reuse hT0 as hid[seq][j]
    }
    __syncthreads();
    if (tid < G) {
        float ssum = fc2_b[0];
        #pragma unroll
        for (int j = 0; j < 32; ++j) ssum += hT0[tid * HPAD + j] * fc2_w[j];
        out[seq0 + tid] = fmaxf(ssum, 0.f);
    }
}

// ---------------------------------------------------------------------------
extern "C" void kernel_launch(void* const* d_in, const int* in_sizes, int n_in,
                              void* d_out, int out_size, void* d_ws, size_t ws_size,
                              hipStream_t stream)
{
    const float* g_data = (const float*)d_in[0];
    const float* weights = (const float*)d_in[1];
    const float* Wih0   = (const float*)d_in[2];
    const float* Whh0   = (const float*)d_in[3];
    const float* bih0   = (const float*)d_in[4];
    const float* bhh0   = (const float*)d_in[5];
    const float* Wih1   = (const float*)d_in[6];
    const float* Whh1   = (const float*)d_in[7];
    const float* bih1   = (const float*)d_in[8];
    const float* bhh1   = (const float*)d_in[9];
    const float* fc1_w  = (const float*)d_in[10];
    const float* fc1_b  = (const float*)d_in[11];
    const float* fc2_w  = (const float*)d_in[12];
    const float* fc2_b  = (const float*)d_in[13];
    float* out = (float*)d_out;

    float* ws     = (float*)d_ws;
    float* x      = ws;                  // 497664
    float* WT0    = x + NSEQ * T_STEPS;  // 65536
    float* WT1i   = WT0 + 65536;         // 65536
    float* WT1h   = WT1i + 65536;        // 65536
    float* wih0p  = WT1h + 65536;        // 512
    float* b0p    = wih0p + 512;         // 512
    float* b1p    = b0p + 512;           // 512

    prep_kernel<<<774, 256, 0, stream>>>(Whh0, Wih1, Whh1, Wih0, bih0, bhh0, bih1, bhh1,
                                         WT0, WT1i, WT1h, wih0p, b0p, b1p);
    income_kernel<<<1944, 256, 0, stream>>>(g_data, weights, x);
    lstm_main<<<NSEQ / G, 256, 0, stream>>>(x, WT0, WT1i, WT1h, wih0p, b0p, b1p,
                                            fc1_w, fc1_b, fc2_w, fc2_b, out);
}